// Round 10
// baseline (191.220 us; speedup 1.0000x reference)
//
#include <hip/hip_runtime.h>
#include <hip/hip_bf16.h>

#define BQ 8
#define TT 1024
#define CC 768
#define NH 12
#define HD 64
#define BH (BQ*NH)      // 96
#define MROWS (BQ*TT)   // 8192
#define NQKV (3*CC)     // 2304
#define KD CC           // 768

typedef unsigned short u16;
typedef __attribute__((ext_vector_type(4))) short short4v;
typedef __attribute__((ext_vector_type(8))) short short8v;
typedef __attribute__((ext_vector_type(4))) float floatx4;
typedef __attribute__((address_space(1))) const unsigned int gu32;
typedef __attribute__((address_space(3))) unsigned int lu32;

__device__ __forceinline__ float bf2f(u16 u) {
  union { unsigned int i; float f; } c; c.i = ((unsigned int)u) << 16; return c.f;
}
__device__ __forceinline__ u16 f2bf(float f) {
  union { __hip_bfloat16 h; u16 u; } c;
  c.h = __float2bfloat16(f);
  return c.u;
}
__device__ __forceinline__ float fast_exp2(float x) {
  return __builtin_amdgcn_exp2f(x);   // v_exp_f32 (base-2)
}
// async global->LDS, 16 B per lane; LDS dest = wave-uniform base + lane*16
__device__ __forceinline__ void async_ld16(const u16* g, u16* l) {
  __builtin_amdgcn_global_load_lds((gu32*)g, (lu32*)l, 16, 0, 0);
}

// ---------------- fused prep: x->bf16 + 2 weight transposes + mv zero + mask scan ----------------
#define PREP_CONV 6144
#define PREP_WA   1728
#define PREP_WP   576
#define PREP_TOTAL (PREP_CONV + PREP_WA + PREP_WP)   // 8448; +1 zero block, +1 scan block

__global__ __launch_bounds__(256) void prep_kernel(
    const float* __restrict__ x, u16* __restrict__ xb,
    const float* __restrict__ Wattn, u16* __restrict__ WtA,
    const float* __restrict__ Wproj, u16* __restrict__ WtP,
    float* __restrict__ mvz,
    const int* __restrict__ maskp, int* __restrict__ tidx, int* __restrict__ nbv)
{
  __shared__ float tile[32][33];
  int bid = blockIdx.x;
  int tid = threadIdx.x;
  if (bid == PREP_TOTAL) {   // zero vmean accumulator
    for (int i = tid; i < BH * HD; i += 256) mvz[i] = 0.f;
    return;
  }
  if (bid == PREP_TOTAL + 1) {   // mask scan: compact unmasked row indices per batch
    int lane = tid & 63, w = tid >> 6;
    for (int b2 = w; b2 < BQ; b2 += 4) {
      int base = 0;
#pragma unroll 1
      for (int ch = 0; ch < 16; ++ch) {
        int t = (ch << 6) + lane;
        int m = maskp[b2 * TT + t];
        unsigned long long bm = __ballot(m != 0);
        int pre = __builtin_popcountll(bm & ((1ull << lane) - 1ull));
        if (m != 0) tidx[b2 * TT + base + pre] = t;
        base += __builtin_popcountll(bm);
      }
      if (lane == 0) nbv[b2] = base;
      for (int i = base + lane; i < TT; i += 64) tidx[b2 * TT + i] = TT - 1;  // pad
    }
    return;
  }
  if (bid < PREP_CONV) {
    int i = (bid * 256 + tid) * 4;
    floatx4 v = *(const floatx4*)(x + i);
    short4v o;
    o[0] = (short)f2bf(v[0]); o[1] = (short)f2bf(v[1]);
    o[2] = (short)f2bf(v[2]); o[3] = (short)f2bf(v[3]);
    *(short4v*)(xb + i) = o;
    return;
  }
  const float* in; u16* out; int R, Cc, b2;
  if (bid < PREP_CONV + PREP_WA) { in = Wattn; out = WtA; R = KD; Cc = NQKV; b2 = bid - PREP_CONV; }
  else                           { in = Wproj; out = WtP; R = CC; Cc = CC;   b2 = bid - PREP_CONV - PREP_WA; }
  int ct = Cc >> 5;
  int bx = b2 % ct;
  int by = b2 / ct;
  int tx = tid & 31;
  int ty = tid >> 5;    // 0..7
  int c0 = bx << 5, r0 = by << 5;
#pragma unroll
  for (int s = 0; s < 4; ++s)
    tile[ty + s*8][tx] = in[(size_t)(r0 + ty + s*8) * Cc + c0 + tx];
  __syncthreads();
#pragma unroll
  for (int s = 0; s < 4; ++s)
    out[(size_t)(c0 + ty + s*8) * R + r0 + tx] = f2bf(tile[tx][ty + s*8]);
}

// ------- GEMM: 64x128 tile, BK=64, global_load_lds + XOR bank swizzle -------
// mode 0: q/k scattered directly; V written TRANSPOSED to vtb [bh][d][t] via
//         LDS staging; vmean partials from f32 accs. mode 1: f32 row-major out.
__global__ __launch_bounds__(256) void gemm_bt(
    const u16* __restrict__ A, const u16* __restrict__ Bt,
    const float* __restrict__ bias,
    float* __restrict__ out,
    u16* __restrict__ qo, u16* __restrict__ ko, u16* __restrict__ vo,
    float* __restrict__ mvp,
    int M, int N, int mode)
{
  __shared__ u16 smem[64 * 64 + 128 * 64];   // As | Bs ; reused as V-staging (needs 128*72)
  u16* Asm = smem;
  u16* Bsm = smem + 64 * 64;

  int tid = threadIdx.x;
  int lane = tid & 63;
  int w = tid >> 6;
  int c = lane & 15;     // fragment col
  int q4 = lane >> 4;    // quad

  int mtiles = M >> 6;
  int mt = blockIdx.x % mtiles;
  int nt = blockIdx.x / mtiles;
  int m0 = mt << 6, n0 = nt << 7;

  int wr = (w >> 1) << 5;   // 0 / 32
  int wc = (w & 1) << 6;    // 0 / 64

  int srow8 = lane >> 3;                      // 0..7
  int ug = ((lane & 7) ^ srow8) << 3;         // swizzled global k-offset (shorts)
  const u16* ag = A  + (size_t)(m0 + w * 16 + srow8) * KD + ug;
  const u16* bg = Bt + (size_t)(n0 + w * 32 + srow8) * KD + ug;
  u16* asl = &Asm[(w * 16) * 64];
  u16* bsl = &Bsm[(w * 32) * 64];

  floatx4 acc[2][4];
#pragma unroll
  for (int mi = 0; mi < 2; ++mi)
#pragma unroll
    for (int ni = 0; ni < 4; ++ni) acc[mi][ni] = (floatx4){0.f, 0.f, 0.f, 0.f};

  int c7 = c & 7;

#pragma unroll 1
  for (int kt = 0; kt < KD; kt += 64) {
    async_ld16(ag + kt,              asl);
    async_ld16(ag + kt + 8 * KD,     asl + 8 * 64);
    async_ld16(bg + kt,              bsl);
    async_ld16(bg + kt + 8 * KD,     bsl + 8 * 64);
    async_ld16(bg + kt + 16 * KD,    bsl + 16 * 64);
    async_ld16(bg + kt + 24 * KD,    bsl + 24 * 64);
    __syncthreads();

    short8v af[2][2], bf[4][2];
#pragma unroll
    for (int kc = 0; kc < 2; ++kc) {
      int uoff = ((kc * 4 + q4) ^ c7) << 3;
#pragma unroll
      for (int mi = 0; mi < 2; ++mi)
        af[mi][kc] = *(const short8v*)&Asm[(wr + mi * 16 + c) * 64 + uoff];
#pragma unroll
      for (int ni = 0; ni < 4; ++ni)
        bf[ni][kc] = *(const short8v*)&Bsm[(wc + ni * 16 + c) * 64 + uoff];
    }
#pragma unroll
    for (int kc = 0; kc < 2; ++kc)
#pragma unroll
      for (int mi = 0; mi < 2; ++mi)
#pragma unroll
        for (int ni = 0; ni < 4; ++ni)
          acc[mi][ni] = __builtin_amdgcn_mfma_f32_16x16x32_bf16(af[mi][kc], bf[ni][kc], acc[mi][ni], 0, 0, 0);
    __syncthreads();
  }

  if (mode == 0) {
    int which = (n0 + wc) / CC;          // per-wave (128-blocks can straddle q/k and k/v)
    int nbase = (n0 + wc) - which * CC;
    int bb = m0 >> 10;                   // m-range (64) never straddles a batch
    int t0 = m0 & 1023;

    if (which < 2) {
      // direct scatter: 16 c-lanes cover a contiguous 32B segment -> coalesces
      u16* dst0 = (which == 0) ? qo : ko;
#pragma unroll
      for (int ni = 0; ni < 4; ++ni) {
        int nn = nbase + ni * 16 + c;
        int hh = nn >> 6, dd = nn & 63;
        float bv = bias[which * CC + nn];
#pragma unroll
        for (int mi = 0; mi < 2; ++mi) {
#pragma unroll
          for (int r = 0; r < 4; ++r) {
            int tt2 = t0 + wr + mi * 16 + q4 * 4 + r;
            dst0[(((size_t)(bb * NH + hh)) * TT + tt2) * HD + dd] = f2bf(acc[mi][ni][r] + bv);
          }
        }
      }
    }
    // V path: block-uniform wrapper (n0 is uniform) -> barrier is legal
    if (n0 + 127 >= 2 * CC) {
      u16* Ct = smem;                    // [128 n][64 t] stride 72 (18432B <= 24576)
      if (which == 2) {
#pragma unroll
        for (int ni = 0; ni < 4; ++ni) {
          float bv = bias[2 * CC + nbase + ni * 16 + c];
#pragma unroll
          for (int mi = 0; mi < 2; ++mi) {
            short4v pk;
#pragma unroll
            for (int r = 0; r < 4; ++r) pk[r] = (short)f2bf(acc[mi][ni][r] + bv);
            *(short4v*)&Ct[(wc + ni * 16 + c) * 72 + wr + mi * 16 + q4 * 4] = pk;
          }
        }
      }
      __syncthreads();
#pragma unroll
      for (int j = 0; j < 4; ++j) {
        int flat = tid + j * 256;        // [128 rows][8 units of 16B]
        int drow = flat >> 3, u = flat & 7;
        int nn2 = n0 + drow;
        if (nn2 >= 2 * CC) {
          int nv = nn2 - 2 * CC;
          int h2 = nv >> 6, d2 = nv & 63;
          short8v val = *(const short8v*)&Ct[drow * 72 + u * 8];
          *(short8v*)&vo[(((size_t)(bb * NH + h2)) * HD + d2) * TT + t0 + u * 8] = val;
        }
      }
      // vmean partials from f32 accs (+bias): each wave sums its 32 t-rows
      if (which == 2) {
        int hw = nbase >> 6;             // wave covers exactly one head
        int bhw = bb * NH + hw;
#pragma unroll
        for (int ni = 0; ni < 4; ++ni) {
          float bv = bias[2 * CC + nbase + ni * 16 + c];
          float s = 8.0f * bv;
#pragma unroll
          for (int mi = 0; mi < 2; ++mi)
#pragma unroll
            for (int r = 0; r < 4; ++r) s += acc[mi][ni][r];
          s += __shfl_xor(s, 16);
          s += __shfl_xor(s, 32);        // sum over this wave's 32 rows
          if (q4 == 0) atomicAdd(&mvp[bhw * HD + ni * 16 + c], s);
        }
      }
    }
  } else {
#pragma unroll
    for (int ni = 0; ni < 4; ++ni) {
      int nn = n0 + wc + ni * 16 + c;
      float bv = bias[nn];
#pragma unroll
      for (int mi = 0; mi < 2; ++mi) {
#pragma unroll
        for (int r = 0; r < 4; ++r) {
          int mm = m0 + wr + mi * 16 + q4 * 4 + r;
          out[(size_t)mm * N + nn] = acc[mi][ni][r] + bv;
        }
      }
    }
  }
}

// ------- proj GEMM: 64x64 tile, BK=64, 1536 blocks -------
__global__ __launch_bounds__(256) void gemm_proj(
    const u16* __restrict__ A, const u16* __restrict__ Bt,
    const float* __restrict__ bias, float* __restrict__ out)
{
  __shared__ u16 As[64 * 64];
  __shared__ u16 Bs[64 * 64];

  int tid = threadIdx.x;
  int lane = tid & 63;
  int w = tid >> 6;
  int c = lane & 15;
  int q4 = lane >> 4;

  int mt = blockIdx.x & 127;      // 128 mtiles
  int nt = blockIdx.x >> 7;       // 12 ntiles
  int m0 = mt << 6, n0 = nt << 6;

  int wr = (w >> 1) << 5;   // 0 / 32
  int wc = (w & 1) << 5;    // 0 / 32

  int srow8 = lane >> 3;
  int ug = ((lane & 7) ^ srow8) << 3;
  const u16* ag = A  + (size_t)(m0 + w * 16 + srow8) * KD + ug;
  const u16* bg = Bt + (size_t)(n0 + w * 16 + srow8) * KD + ug;
  u16* asl = &As[(w * 16) * 64];
  u16* bsl = &Bs[(w * 16) * 64];

  floatx4 acc[2][2];
#pragma unroll
  for (int mi = 0; mi < 2; ++mi)
#pragma unroll
    for (int ni = 0; ni < 2; ++ni) acc[mi][ni] = (floatx4){0.f, 0.f, 0.f, 0.f};

  int c7 = c & 7;

#pragma unroll 1
  for (int kt = 0; kt < KD; kt += 64) {
    async_ld16(ag + kt,          asl);
    async_ld16(ag + kt + 8 * KD, asl + 8 * 64);
    async_ld16(bg + kt,          bsl);
    async_ld16(bg + kt + 8 * KD, bsl + 8 * 64);
    __syncthreads();

    short8v af[2][2], bf[2][2];
#pragma unroll
    for (int kc = 0; kc < 2; ++kc) {
      int uoff = ((kc * 4 + q4) ^ c7) << 3;
#pragma unroll
      for (int mi = 0; mi < 2; ++mi)
        af[mi][kc] = *(const short8v*)&As[(wr + mi * 16 + c) * 64 + uoff];
#pragma unroll
      for (int ni = 0; ni < 2; ++ni)
        bf[ni][kc] = *(const short8v*)&Bs[(wc + ni * 16 + c) * 64 + uoff];
    }
#pragma unroll
    for (int kc = 0; kc < 2; ++kc)
#pragma unroll
      for (int mi = 0; mi < 2; ++mi)
#pragma unroll
        for (int ni = 0; ni < 2; ++ni)
          acc[mi][ni] = __builtin_amdgcn_mfma_f32_16x16x32_bf16(af[mi][kc], bf[ni][kc], acc[mi][ni], 0, 0, 0);
    __syncthreads();
  }

#pragma unroll
  for (int ni = 0; ni < 2; ++ni) {
    int nn = n0 + wc + ni * 16 + c;
    float bv = bias[nn];
#pragma unroll
    for (int mi = 0; mi < 2; ++mi) {
#pragma unroll
      for (int r = 0; r < 4; ++r) {
        int mm = m0 + wr + mi * 16 + q4 * 4 + r;
        out[(size_t)mm * CC + nn] = acc[mi][ni][r] + bv;
      }
    }
  }
}

// ---------------- MFMA flash attention on MASK-COMPACTED q-rows ----------------
// ~50% of rows are masked (output replaced by vmean) -> attention runs only on
// compacted unmasked rows (tidx per batch, sorted; ~8 q-tiles instead of 16).
// Per-row causal bound: kill key > tidx[row] (exact: keys untouched, t-order kept).
// Tail-tile pad rows read valid memory (t=TT-1), produce finite garbage, never
// written. Fill blocks (bid >= BH*16) write vmean to masked rows.
#define LDW 72
#define SCL 0.18033688f   // (1/sqrt(64)) * log2(e); softmax in exp2 domain

__global__ __launch_bounds__(256, 3) void attn_kernel(
    const u16* __restrict__ qb, const u16* __restrict__ kb,
    const u16* __restrict__ vtb, const int* __restrict__ mask,
    const float* __restrict__ meanv,
    const int* __restrict__ tidx, const int* __restrict__ nbv,
    u16* __restrict__ outb)
{
  __shared__ u16 Ks[2][64 * LDW];    // K tile [key][d], double-buffered
  __shared__ u16 Vs[2][64 * LDW];    // V^T tile [d][key], double-buffered
  __shared__ u16 Ps[4][16 * LDW];    // per-wave P [row][key]

  int bid = blockIdx.x;
  int tid = threadIdx.x;

  if (bid >= BH * 16) {
    // ---- masked-row fill: write vmean to rows with mask==0 ----
    int bh2 = bid - BH * 16;
    int b2 = bh2 / NH, h2 = bh2 - b2 * NH;
    int dch = (tid & 3) << 4;
    short8v v0, v1;
#pragma unroll
    for (int j = 0; j < 8; ++j) {
      v0[j] = (short)f2bf(meanv[bh2 * HD + dch + j] * 0.0009765625f);
      v1[j] = (short)f2bf(meanv[bh2 * HD + dch + 8 + j] * 0.0009765625f);
    }
#pragma unroll 1
    for (int t = tid >> 2; t < TT; t += 64) {
      if (mask[b2 * TT + t] == 0) {
        u16* dst = outb + ((size_t)(b2 * TT + t)) * CC + h2 * HD + dch;
        *(short8v*)dst = v0;
        *(short8v*)(dst + 8) = v1;
      }
    }
    return;
  }

  int lane = tid & 63;
  int w = tid >> 6;
  int c = lane & 15;
  int q4 = lane >> 4;

  // XCD-aware bijective swizzle: 1536 blocks, 192 per XCD = 12 bh per XCD
  int lbid = (bid & 7) * 192 + (bid >> 3);
  int tile = lbid & 15;
  int bh = lbid >> 4;
  int b = bh / NH;
  int h = bh - b * NH;

  int nb = nbv[b];
  int ntiles = (nb + 63) >> 6;
  if (tile >= ntiles) return;

  const int* tix = tidx + b * TT;
  int last = tile * 64 + 63; if (last > nb - 1) last = nb - 1;
  int ktmax = (tix[last] >> 6) + 1;          // k-tiles needed for this q-tile

  int rowc = tile * 64 + (w << 4) + c;       // compact row this lane owns (softmax)
  int tqc = tix[rowc];                       // original t (pad rows -> TT-1)

  int srow = tid >> 2;
  int schunk = (tid & 3) << 4;
  const u16* kgp = kb + ((size_t)bh * TT + srow) * HD + schunk;
  const u16* vgp = vtb + ((size_t)bh * HD + srow) * TT + schunk;
  u16* pw = &Ps[w][0];

  short8v onesv;
#pragma unroll
  for (int j = 0; j < 8; ++j) onesv[j] = (short)0x3F80;   // bf16 1.0

  short8v qfrag[2];
  {
    const u16* qp = qb + ((size_t)bh * TT + tqc) * HD + q4 * 8;   // gathered q-row
    qfrag[0] = *(const short8v*)qp;
    qfrag[1] = *(const short8v*)(qp + 32);
  }

  floatx4 o[4];
#pragma unroll
  for (int i = 0; i < 4; ++i) o[i] = (floatx4){0.f, 0.f, 0.f, 0.f};
  floatx4 o5 = (floatx4){0.f, 0.f, 0.f, 0.f};   // row-sum accumulator (l)

  // prologue: tile 0 into buffer 0
  short8v kr0 = *(const short8v*)kgp;
  short8v kr1 = *(const short8v*)(kgp + 8);
  short8v vr0 = *(const short8v*)vgp;
  short8v vr1 = *(const short8v*)(vgp + 8);
  {
    u16* kd = &Ks[0][srow * LDW + schunk];
    u16* vd = &Vs[0][srow * LDW + schunk];
    *(short8v*)kd = kr0; *(short8v*)(kd + 8) = kr1;
    *(short8v*)vd = vr0; *(short8v*)(vd + 8) = vr1;
  }

#pragma unroll 1
  for (int kt = 0; kt < ktmax; ++kt) {
    int cur = kt & 1;
    __syncthreads();               // buf[cur] staged; prior reads of buf[cur^1] done

    if (kt + 1 < ktmax) {          // issue next-tile loads early
      const u16* kp = kgp + ((size_t)(kt + 1) << 6) * HD;
      const u16* vp = vgp + ((kt + 1) << 6);
      kr0 = *(const short8v*)kp;
      kr1 = *(const short8v*)(kp + 8);
      vr0 = *(const short8v*)vp;
      vr1 = *(const short8v*)(vp + 8);
    }

    // S^T: s[nt] holds S[key=nt*16+q4*4+r][qrow=c]
    floatx4 s[4];
#pragma unroll
    for (int nt = 0; nt < 4; ++nt) s[nt] = (floatx4){0.f, 0.f, 0.f, 0.f};
    __builtin_amdgcn_s_setprio(1);
#pragma unroll
    for (int kc = 0; kc < 2; ++kc) {
#pragma unroll
      for (int nt = 0; nt < 4; ++nt) {
        short8v kf = *(const short8v*)&Ks[cur][(nt * 16 + c) * LDW + kc * 32 + q4 * 8];
        s[nt] = __builtin_amdgcn_mfma_f32_16x16x32_bf16(kf, qfrag[kc], s[nt], 0, 0, 0);
      }
    }
    __builtin_amdgcn_s_setprio(0);

    // p = exp2(s*SCL); per-row causal kill: key > tqc (exact for compacted rows)
    int kbase = kt << 6;
#pragma unroll
    for (int nt = 0; nt < 4; ++nt) {
      short4v pk;
#pragma unroll
      for (int r = 0; r < 4; ++r) {
        float sv = s[nt][r];
        if (kbase + nt * 16 + (q4 << 2) + r > tqc) sv = -INFINITY;
        pk[r] = (short)f2bf(fast_exp2(sv * SCL));
      }
      *(short4v*)&pw[c * LDW + nt * 16 + (q4 << 2)] = pk;
    }

    if (kt + 1 < ktmax) {          // write next tile while this one is consumed
      u16* kd = &Ks[cur ^ 1][srow * LDW + schunk];
      u16* vd = &Vs[cur ^ 1][srow * LDW + schunk];
      *(short8v*)kd = kr0; *(short8v*)(kd + 8) = kr1;
      *(short8v*)vd = vr0; *(short8v*)(vd + 8) = vr1;
    }

    // PV + row-sum: O += P*Vt, l += P*1   (P wave-private, no barrier)
    __builtin_amdgcn_s_setprio(1);
#pragma unroll
    for (int kc = 0; kc < 2; ++kc) {
      short8v pf = *(const short8v*)&pw[c * LDW + kc * 32 + q4 * 8];
#pragma unroll
      for (int nt = 0; nt < 4; ++nt) {
        short8v vf = *(const short8v*)&Vs[cur][(nt * 16 + c) * LDW + kc * 32 + q4 * 8];
        o[nt] = __builtin_amdgcn_mfma_f32_16x16x32_bf16(pf, vf, o[nt], 0, 0, 0);
      }
      o5 = __builtin_amdgcn_mfma_f32_16x16x32_bf16(pf, onesv, o5, 0, 0, 0);
    }
    __builtin_amdgcn_s_setprio(0);
  }

  // epilogue: scatter to original rows; pad rows (compact >= nb) skipped
  int crow0 = tile * 64 + (w << 4) + (q4 << 2);
  int trow[4]; bool valid[4]; float inv[4];
#pragma unroll
  for (int r = 0; r < 4; ++r) {
    valid[r] = (crow0 + r) < nb;
    trow[r] = tix[crow0 + r];
    inv[r] = 1.f / o5[r];
  }
#pragma unroll
  for (int nt = 0; nt < 4; ++nt) {
    int d = nt * 16 + c;
#pragma unroll
    for (int r = 0; r < 4; ++r) {
      if (valid[r])
        outb[((size_t)(b * TT + trow[r])) * CC + h * HD + d] = f2bf(o[nt][r] * inv[r]);
    }
  }
}

// ---------------- launcher ----------------
extern "C" void kernel_launch(void* const* d_in, const int* in_sizes, int n_in,
                              void* d_out, int out_size, void* d_ws, size_t ws_size,
                              hipStream_t stream)
{
  (void)in_sizes; (void)n_in; (void)out_size; (void)ws_size;
  const float* x     = (const float*)d_in[0];
  const int*   mask  = (const int*)d_in[1];
  const float* Wattn = (const float*)d_in[2];
  const float* battn = (const float*)d_in[3];
  const float* Wproj = (const float*)d_in[4];
  const float* bproj = (const float*)d_in[5];
  float* out = (float*)d_out;

  char* ws = (char*)d_ws;
  size_t off = 0;
  auto alloc = [&](size_t bytes) -> void* {
    void* p = ws + off;
    off += (bytes + 255) & ~(size_t)255;
    return p;
  };
  u16* WtA  = (u16*)alloc((size_t)NQKV * KD * 2);
  u16* WtP  = (u16*)alloc((size_t)CC * CC * 2);
  u16* xb   = (u16*)alloc((size_t)MROWS * CC * 2);
  u16* qbuf = (u16*)alloc((size_t)MROWS * CC * 2);
  u16* kbuf = (u16*)alloc((size_t)MROWS * CC * 2);
  u16* vtb  = (u16*)alloc((size_t)MROWS * CC * 2);   // V^T [bh][d][t] (written by gemm0)
  u16* abuf = (u16*)alloc((size_t)MROWS * CC * 2);
  float* mv = (float*)alloc((size_t)BH * HD * 4);
  int* tidx = (int*)alloc((size_t)BQ * TT * 4);      // compacted row indices
  int* nbv  = (int*)alloc((size_t)BQ * 4);           // unmasked counts

  prep_kernel<<<PREP_TOTAL + 2, 256, 0, stream>>>(x, xb, Wattn, WtA, Wproj, WtP,
                                                  mv, mask, tidx, nbv);

  gemm_bt<<<(MROWS/64)*(NQKV/128), 256, 0, stream>>>(
      xb, WtA, battn, nullptr, qbuf, kbuf, vtb, mv, MROWS, NQKV, 0);

  attn_kernel<<<BH * 16 + BH, 256, 0, stream>>>(qbuf, kbuf, vtb, mask, mv,
                                                tidx, nbv, abuf);

  gemm_proj<<<(MROWS/64)*(CC/64), 256, 0, stream>>>(abuf, WtP, bproj, out);
}